// Round 7
// baseline (221.064 us; speedup 1.0000x reference)
//
#include <hip/hip_runtime.h>
#include <stdint.h>

typedef unsigned short u16;
typedef __attribute__((ext_vector_type(8))) short bf16x8;
typedef __attribute__((ext_vector_type(4))) float f32x4;

#define MFMA16(a, b, c) __builtin_amdgcn_mfma_f32_16x16x32_bf16((a), (b), (c), 0, 0, 0)

__device__ __forceinline__ float b2f(u16 u) {
    union { unsigned int i; float f; } v; v.i = ((unsigned int)u) << 16; return v.f;
}
__device__ __forceinline__ u16 f2b(float f) {
    union { float f; unsigned int i; } v; v.f = f;
    unsigned int r = v.i + 0x7fffu + ((v.i >> 16) & 1u);
    return (u16)(r >> 16);
}
// native 2^x (v_exp_f32); schedulable asm, no memory clobber
__device__ __forceinline__ float exp2_fast(float x) {
    float r; __asm__("v_exp_f32 %0, %1" : "=v"(r) : "v"(x)); return r;
}

typedef __attribute__((address_space(1))) void gvoid;
typedef __attribute__((address_space(3))) void lvoid;
__device__ __forceinline__ void gld16(const void* g, void* l) {
    __builtin_amdgcn_global_load_lds((gvoid*)(void*)g, (lvoid*)l, 16, 0, 0);
}

// Panel-swizzled block mapping: 8-row-tile panels, col-major inside a panel.
// Keeps A's reuse window ~1.6 MB -> L2-resident (FETCH 139->52 MB, measured R5).
__device__ __forceinline__ void tile_from_bid(int bid, int nTM, int nTN,
                                              int& rt, int& ct) {
    const int PW = 8;
    const int full = nTM / PW;
    const int per = PW * nTN;
    int p = bid / per;
    int pw = PW;
    int rem = bid - p * per;
    if (p >= full) { p = full; rem = bid - full * per; pw = nTM - full * PW; }
    const int c = rem / pw;
    const int r = rem - c * pw;
    rt = p * PW + r;
    ct = c;
}

// ---------------------------------------------------------------------------
// fp32 -> bf16 elementwise convert (n multiple of 4)
// ---------------------------------------------------------------------------
__global__ __launch_bounds__(256) void f32_to_bf16(const float* __restrict__ in,
                                                   u16* __restrict__ out, int n) {
    const int i = (blockIdx.x * 256 + threadIdx.x) * 4;
    if (i + 3 < n) {
        const float4 v = *(const float4*)(in + i);
        ushort4 o;
        o.x = f2b(v.x); o.y = f2b(v.y); o.z = f2b(v.z); o.w = f2b(v.w);
        *(ushort4*)(out + i) = o;
    }
}

// ---------------------------------------------------------------------------
// merged transpose + fp32->bf16 for BOTH weights (one launch):
//   blockIdx.x <  72: w_qkv (768 x 2304) -> wqkvT (2304 x 768)
//   blockIdx.x >= 72: w_proj (768 x 768) -> wprojT (768 x 768)
// ---------------------------------------------------------------------------
__global__ __launch_bounds__(256) void transpose_w(const float* __restrict__ wqkv,
                                                   const float* __restrict__ wproj,
                                                   u16* __restrict__ outQ,
                                                   u16* __restrict__ outP) {
    __shared__ float tile[32][33];
    int bx = blockIdx.x;
    const float* in; u16* out; int C;
    if (bx < 72) { in = wqkv; out = outQ; C = 2304; }
    else         { bx -= 72; in = wproj; out = outP; C = 768; }
    const int R = 768;
    const int t = threadIdx.x;
    const int r = t >> 3, c4 = (t & 7) * 4;
    const int ir = blockIdx.y * 32 + r, ic = bx * 32 + c4;
    const float4 v = *(const float4*)(in + (size_t)ir * C + ic);
    tile[r][c4 + 0] = v.x; tile[r][c4 + 1] = v.y;
    tile[r][c4 + 2] = v.z; tile[r][c4 + 3] = v.w;
    __syncthreads();
    const int orow = bx * 32 + r, ocol = blockIdx.y * 32 + c4;
    ushort4 o;
    o.x = f2b(tile[c4 + 0][r]); o.y = f2b(tile[c4 + 1][r]);
    o.z = f2b(tile[c4 + 2][r]); o.w = f2b(tile[c4 + 3][r]);
    *(ushort4*)(out + (size_t)orow * R + ocol) = o;
}

// ---------------------------------------------------------------------------
// C = A(bf16)[M x K] * Bt(bf16)[N x K]^T + bias(f32)[N]
// REVERTED to the R4-proven structure (58.9 us measured): 128x128 tile,
// BK=64, 512 threads = 8 waves in 2x4 (wave 64x32, acc[4][2]), 2-buffer
// LDS (64 KB -> 2 blocks/CU), one __syncthreads per K-step. R6's 256x128 +
// 3-buffer counted-vmcnt at 1 block/CU REGRESSED (66 us): on this problem
// cross-block TLP > intra-block pipeline depth (measured twice: R1, R6).
// Coalesced staging (8 rows x 128B full lines per wave-instr) + XOR
// involution on both sides; SQ_LDS_BANK_CONFLICT == 0 (measured R2/R4).
// MFMA operands swapped (D^T: l15 = row, quad*4+r = 4 cols).
// EPI: 1 = f32 store (stride N);
//      2 = fused qkv epilogue (block-uniform branch on col0):
//          Q/K tiles: bias + RoPE (intra-lane pairs) -> qkv (stride 1536);
//          V tiles: bias -> stores contiguous along l15 into VtG[bh][d][n].
// ---------------------------------------------------------------------------
template <int EPI>
__global__ __launch_bounds__(512) void gemm_bt(const u16* __restrict__ A,
                                               const u16* __restrict__ Bt,
                                               const float* __restrict__ bias,
                                               void* __restrict__ Cv,
                                               const float* __restrict__ cosp,
                                               const float* __restrict__ sinp,
                                               u16* __restrict__ VtG,
                                               int M, int N, int K) {
    __shared__ __align__(16) u16 As0[128 * 64];
    __shared__ __align__(16) u16 As1[128 * 64];
    __shared__ __align__(16) u16 Bs0[128 * 64];
    __shared__ __align__(16) u16 Bs1[128 * 64];

    const int t = threadIdx.x;
    const int lane = t & 63;
    const int wave = t >> 6;              // 0..7
    const int l15 = lane & 15, quad = lane >> 4;
    const int wm = wave >> 2;             // 0..1 (64 rows each)
    const int wn = wave & 3;              // 0..3 (32 cols each)

    int rt, ct;
    tile_from_bid(blockIdx.y * gridDim.x + blockIdx.x, gridDim.x, gridDim.y, rt, ct);
    const int row0 = rt * 128;
    const int col0 = ct * 128;

    const f32x4 fz = {0.f, 0.f, 0.f, 0.f};
    f32x4 acc[4][2];
#pragma unroll
    for (int i = 0; i < 4; ++i)
#pragma unroll
        for (int j = 0; j < 2; ++j) acc[i][j] = fz;

    // Coalesced staging map: chunk g -> row g>>3, LDS slot g&7,
    // global slot (g&7)^(row&7) (XOR source pre-swizzle; involution).
    const u16* Ap[2];
    const u16* Bp[2];
    int off[2];
#pragma unroll
    for (int n = 0; n < 2; ++n) {
        const int g = t + n * 512;
        const int row = g >> 3;
        const int slot = (g & 7) ^ (row & 7);
        int ar = row0 + row; if (ar > M - 1) ar = M - 1;   // clamp partial M tile
        Ap[n] = A + (size_t)ar * K + slot * 8;
        Bp[n] = Bt + (size_t)(col0 + row) * K + slot * 8;  // N % 128 == 0
        off[n] = g * 8;                                    // u16 units (linear LDS)
    }

#define STAGE(kt_, Ad, Bd) do {                                            \
        const int kb_ = (kt_) << 6;                                        \
        gld16(Ap[0] + kb_, (Ad) + off[0]);                                 \
        gld16(Ap[1] + kb_, (Ad) + off[1]);                                 \
        gld16(Bp[0] + kb_, (Bd) + off[0]);                                 \
        gld16(Bp[1] + kb_, (Bd) + off[1]);                                 \
    } while (0)

    // Row-major [row][64] LDS; k-granule XOR-swizzled by l15&7.
#define COMPUTE(Asb, Bsb) do {                                             \
        _Pragma("unroll")                                                  \
        for (int kk = 0; kk < 2; ++kk) {                                   \
            const int swk = ((kk * 4 + quad) ^ (l15 & 7)) * 8;             \
            bf16x8 af[4], bfr[2];                                          \
            _Pragma("unroll")                                              \
            for (int mi = 0; mi < 4; ++mi)                                 \
                af[mi] = *(const bf16x8*)((Asb) +                          \
                    ((wm * 4 + mi) * 16 + l15) * 64 + swk);                \
            _Pragma("unroll")                                              \
            for (int ni = 0; ni < 2; ++ni)                                 \
                bfr[ni] = *(const bf16x8*)((Bsb) +                         \
                    ((wn * 2 + ni) * 16 + l15) * 64 + swk);                \
            _Pragma("unroll")                                              \
            for (int mi = 0; mi < 4; ++mi)                                 \
                _Pragma("unroll")                                          \
                for (int ni = 0; ni < 2; ++ni)                             \
                    acc[mi][ni] = MFMA16(bfr[ni], af[mi], acc[mi][ni]);    \
        }                                                                  \
    } while (0)

    const int nKT = K >> 6;               // even (K % 128 == 0)
    STAGE(0, As0, Bs0);                   // prologue: tile 0 -> buf0
    __syncthreads();                      // (drains vmcnt0)

    for (int kt = 0; kt < nKT; kt += 2) {
        if (kt + 1 < nKT) STAGE(kt + 1, As1, Bs1);   // prefetch next -> buf1
        COMPUTE(As0, Bs0);                           // compute current (buf0)
        __syncthreads();                             // buf1 ready; buf0 released
        if (kt + 2 < nKT) STAGE(kt + 2, As0, Bs0);   // prefetch next -> buf0
        COMPUTE(As1, Bs1);                           // compute current (buf1)
        __syncthreads();                             // buf0 ready; buf1 released
    }
#undef STAGE
#undef COMPUTE

    // ---- epilogue (D^T layout: row = ...+l15, cols = colb..colb+3) ----
    if (EPI == 2) {
        if (col0 >= 1536) {
            // V tiles -> VtG[bh][d][n], stores contiguous along l15 (token n)
#pragma unroll
            for (int mi = 0; mi < 4; ++mi) {
                const int row = row0 + wm * 64 + mi * 16 + l15;
                if (row < M) {
                    const int bb = row / 577, n = row - bb * 577;
                    u16* vdst = VtG + (size_t)bb * 491520 + n;   // 12*64*640
#pragma unroll
                    for (int ni = 0; ni < 2; ++ni) {
                        const int colb = col0 + wn * 32 + ni * 16 + quad * 4;
                        const float4 bv = *(const float4*)(bias + colb);
#pragma unroll
                        for (int r = 0; r < 4; ++r) {
                            const int cv = colb + r - 1536;
                            vdst[(size_t)(cv >> 6) * 40960 + (cv & 63) * 640] =
                                f2b(acc[mi][ni][r] + ((const float*)&bv)[r]);
                        }
                    }
                }
            }
        } else {
            // Q/K tiles: bias + RoPE (intra-lane pairs) -> 1536-stride qkv
#pragma unroll
            for (int mi = 0; mi < 4; ++mi) {
                const int row = row0 + wm * 64 + mi * 16 + l15;
                if (row < M) {
                    const int bb = row / 577, n = row - bb * 577;
                    const bool hr = (n >= 1);
                    const float* cb = cosp + (size_t)(hr ? (n - 1) : 0) * 32;
                    const float* sb = sinp + (size_t)(hr ? (n - 1) : 0) * 32;
                    u16* outp = (u16*)Cv + (size_t)row * 1536;
#pragma unroll
                    for (int ni = 0; ni < 2; ++ni) {
                        const int colb = col0 + wn * 32 + ni * 16 + quad * 4;
                        const float4 bv = *(const float4*)(bias + colb);
                        const int pi = (colb & 63) >> 1;           // even
                        float2 c = *(const float2*)(cb + pi);
                        float2 s = *(const float2*)(sb + pi);
                        if (!hr) { c.x = 1.f; c.y = 1.f; s.x = 0.f; s.y = 0.f; }
                        const float v0 = acc[mi][ni][0] + bv.x;
                        const float v1 = acc[mi][ni][1] + bv.y;
                        const float v2 = acc[mi][ni][2] + bv.z;
                        const float v3 = acc[mi][ni][3] + bv.w;
                        ushort4 o;
                        o.x = f2b(v0 * c.x - v1 * s.x);
                        o.y = f2b(v0 * s.x + v1 * c.x);
                        o.z = f2b(v2 * c.y - v3 * s.y);
                        o.w = f2b(v2 * s.y + v3 * c.y);
                        *(ushort4*)(outp + colb) = o;
                    }
                }
            }
        }
    } else {
#pragma unroll
        for (int ni = 0; ni < 2; ++ni) {
            const int colb = col0 + wn * 32 + ni * 16 + quad * 4;
            const float4 bv = *(const float4*)(bias + colb);
#pragma unroll
            for (int mi = 0; mi < 4; ++mi) {
                const int row = row0 + wm * 64 + mi * 16 + l15;
                if (row < M) {
                    float4 o;
                    o.x = acc[mi][ni][0] + bv.x; o.y = acc[mi][ni][1] + bv.y;
                    o.z = acc[mi][ni][2] + bv.z; o.w = acc[mi][ni][3] + bv.w;
                    *(float4*)((float*)Cv + (size_t)row * N + colb) = o;
                }
            }
        }
    }
}

// ---------------------------------------------------------------------------
// Flash attention R14: SINGLE-buffered K/V staging -> LDS 25.4 KB ->
// ~6 blocks/CU (24 waves, ~75% occupancy; was 42 KB / 3 blocks / 33%).
// R3/R4 showed attn2 is latency-bound on the serial per-tile softmax chain
// with all pipes <40% idle-ish; intra-block prefetch (double-buffer) was
// already tried and the chain remained the limiter. Applying the R4/R6
// lesson (TLP across co-resident blocks > intra-block pipelining): the
// per-tile stage drain is now hidden by 5 other resident blocks.
// Swapped-operand layout (lane owns one query; reductions in-register +
// 2 shfl), base-2 softmax, packed P writes, XCD-chunk swizzle -- unchanged.
// ---------------------------------------------------------------------------
#define PSTR 72
#define CEXP 0.18033688011112042f   /* 0.125 * log2(e) */

__global__ __launch_bounds__(256) void attn2(const u16* __restrict__ qkv,
                                             const u16* __restrict__ VtG,
                                             u16* __restrict__ aout) {
    __shared__ __align__(16) u16 Ks[64 * 64];
    __shared__ __align__(16) u16 Vs[64 * 64];
    __shared__ __align__(16) u16 Pb[4 * 16 * PSTR];

    const int t = threadIdx.x;
    const int lane = t & 63, wave = t >> 6;
    const int l15 = lane & 15, quad = lane >> 4;

    // bijective XCD-chunk swizzle: 1920 blocks = 8 XCDs x 240 contiguous
    const int bid = blockIdx.x;
    const int swz = (bid & 7) * 240 + (bid >> 3);
    const int bh = swz / 10, qt = swz - bh * 10;     // 10 q-tiles per bh
    const int b = bh / 12, h = bh - b * 12;
    const u16* baseQ = qkv + (size_t)b * 577 * 1536 + h * 64;
    const u16* baseK = baseQ + 768;
    const u16* vbase = VtG + (size_t)bh * 64 * 640;

    const int mq = qt * 64 + wave * 16 + l15;        // this lane's query
    const int nq = mq < 577 ? mq : 576;
    bf16x8 aq[2];
    aq[0] = *(const bf16x8*)(baseQ + (size_t)nq * 1536 + quad * 8);
    aq[1] = *(const bf16x8*)(baseQ + (size_t)nq * 1536 + 32 + quad * 8);

    // staging map: chunk g (0..511) -> row g>>3, LDS slot g&7, global slot
    // (g&7)^(row&7). One wave-instr = 8 consecutive rows x 128B full lines.
    const int g0 = t, g1 = t + 256;
    const int r0 = g0 >> 3, r1 = g1 >> 3;
    const int s0 = (g0 & 7) ^ (r0 & 7), s1 = (g1 & 7) ^ (r1 & 7);
    const int o0 = g0 * 8, o1 = g1 * 8;              // u16 units (16B chunks)
    const u16* Kp0 = baseK + (size_t)r0 * 1536 + s0 * 8;   // + kt*64*1536
    const u16* Kp1 = baseK + (size_t)r1 * 1536 + s1 * 8;
    const u16* Vp0 = vbase + (size_t)r0 * 640 + s0 * 8;    // + kt*64
    const u16* Vp1 = vbase + (size_t)r1 * 640 + s1 * 8;
    const u16* K9p0 = baseK + (size_t)576 * 1536 + s0 * 8; // kt=9: all rows
    const u16* K9p1 = baseK + (size_t)576 * 1536 + s1 * 8; // clamp to key 576

    // hoisted XOR'd k-granule offsets (row%8 == l15%8 on every read row)
    const int swk0 = (quad ^ (l15 & 7)) * 8;
    const int swk1 = ((4 + quad) ^ (l15 & 7)) * 8;

    u16* Pw = Pb + wave * 16 * PSTR;

    f32x4 oacc[4];
    const f32x4 fz = {0.f, 0.f, 0.f, 0.f};
#pragma unroll
    for (int i = 0; i < 4; ++i) oacc[i] = fz;
    float m1 = -1e30f;
    float l1 = 0.f;

#define ASTAGE(kt_) do {                                                    \
        gld16(Kp0 + (size_t)(kt_) * 98304, Ks + o0);                        \
        gld16(Kp1 + (size_t)(kt_) * 98304, Ks + o1);                        \
        gld16(Vp0 + (kt_) * 64, Vs + o0);                                   \
        gld16(Vp1 + (kt_) * 64, Vs + o1);                                   \
    } while (0)

#define ASTAGE9() do {                                                      \
        gld16(K9p0, Ks + o0);                                               \
        gld16(K9p1, Ks + o1);                                               \
        gld16(Vp0 + 576, Vs + o0);                                          \
        gld16(Vp1 + 576, Vs + o1);                                          \
    } while (0)

#define ATT_TILE(kt_, MASKED) do {                                          \
        f32x4 sacc[4];                                                      \
        _Pragma("unroll")                                                   \
        for (int nt = 0; nt < 4; ++nt) {                                    \
            sacc[nt] = fz;                                                  \
            const bf16x8 bk0 = *(const bf16x8*)(Ks + (nt * 16 + l15) * 64 + swk0); \
            sacc[nt] = MFMA16(bk0, aq[0], sacc[nt]);                        \
            const bf16x8 bk1 = *(const bf16x8*)(Ks + (nt * 16 + l15) * 64 + swk1); \
            sacc[nt] = MFMA16(bk1, aq[1], sacc[nt]);                        \
        }                                                                   \
        if (MASKED) {                                                       \
            _Pragma("unroll")                                               \
            for (int nt = 0; nt < 4; ++nt)                                  \
                _Pragma("unroll")                                           \
                for (int r = 0; r < 4; ++r)                                 \
                    if (nt * 16 + quad * 4 + r > 0) sacc[nt][r] = -1e30f;   \
        }                                                                   \
        float mA = fmaxf(fmaxf(sacc[0][0], sacc[0][1]), fmaxf(sacc[0][2], sacc[0][3])); \
        float mB = fmaxf(fmaxf(sacc[1][0], sacc[1][1]), fmaxf(sacc[1][2], sacc[1][3])); \
        float mC = fmaxf(fmaxf(sacc[2][0], sacc[2][1]), fmaxf(sacc[2][2], sacc[2][3])); \
        float mD = fmaxf(fmaxf(sacc[3][0], sacc[3][1]), fmaxf(sacc[3][2], sacc[3][3])); \
        float mt = fmaxf(fmaxf(mA, mB), fmaxf(mC, mD));                     \
        mt = fmaxf(mt, __shfl_xor(mt, 16));                                 \
        mt = fmaxf(mt, __shfl_xor(mt, 32));                                 \
        const float mnew = fmaxf(m1, mt);                                   \
        const float alpha = exp2_fast((m1 - mnew) * CEXP);                  \
        m1 = mnew;                                                          \
        const float nmc = -mnew * CEXP;                                     \
        float lsum = 0.f;                                                   \
        _Pragma("unroll")                                                   \
        for (int nt = 0; nt < 4; ++nt) {                                    \
            const float p0 = exp2_fast(__builtin_fmaf(sacc[nt][0], CEXP, nmc)); \
            const float p1 = exp2_fast(__builtin_fmaf(sacc[nt][1], CEXP, nmc)); \
            const float p2 = exp2_fast(__builtin_fmaf(sacc[nt][2], CEXP, nmc)); \
            const float p3 = exp2_fast(__builtin_fmaf(sacc[nt][3], CEXP, nmc)); \
            lsum += (p0 + p1) + (p2 + p3);                                  \
            ushort4 pk;                                                     \
            pk.x = f2b(p0); pk.y = f2b(p1); pk.z = f2b(p2); pk.w = f2b(p3); \
            *(ushort4*)(Pw + l15 * PSTR + nt * 16 + quad * 4) = pk;         \
        }                                                                   \
        _Pragma("unroll")                                                   \
        for (int dt = 0; dt < 4; ++dt) {                                    \
            oacc[dt][0] *= alpha; oacc[dt][1] *= alpha;                     \
            oacc[dt][2] *= alpha; oacc[dt][3] *= alpha;                     \
        }                                                                   \
        __asm__ __volatile__("s_waitcnt lgkmcnt(0)" ::: "memory");          \
        _Pragma("unroll")                                                   \
        for (int kc = 0; kc < 2; ++kc) {                                    \
            const bf16x8 pf = *(const bf16x8*)(Pw + l15 * PSTR + kc * 32 + quad * 8); \
            const int swkv = kc ? swk1 : swk0;                              \
            _Pragma("unroll")                                               \
            for (int dt = 0; dt < 4; ++dt) {                                \
                const bf16x8 vf = *(const bf16x8*)(Vs + (dt * 16 + l15) * 64 + swkv); \
                oacc[dt] = MFMA16(vf, pf, oacc[dt]);                        \
            }                                                               \
        }                                                                   \
        lsum += __shfl_xor(lsum, 16);                                       \
        lsum += __shfl_xor(lsum, 32);                                       \
        l1 = l1 * alpha + lsum;                                             \
    } while (0)

    // single-buffer loop: stage -> publish -> compute; drain hidden by
    // ~6 co-resident blocks (TLP), not by intra-block prefetch.
    for (int kt = 0; kt < 9; ++kt) {
        ASTAGE(kt);
        __syncthreads();                  // vmcnt0 drain + publish
        ATT_TILE(kt, false);
        __syncthreads();                  // all reads done; buffer reusable
    }
    ASTAGE9();
    __syncthreads();
    ATT_TILE(9, true);                    // only tile with invalid keys

#undef ASTAGE
#undef ASTAGE9
#undef ATT_TILE

    // final: lane owns query l15; d = dt*16 + quad*4 + r (packed ushort4)
    const int n = qt * 64 + wave * 16 + l15;
    if (n < 577) {
        const float linv = 1.f / l1;
        u16* op = aout + ((size_t)b * 577 + n) * 768 + h * 64 + quad * 4;
#pragma unroll
        for (int dt = 0; dt < 4; ++dt) {
            ushort4 o;
            o.x = f2b(oacc[dt][0] * linv); o.y = f2b(oacc[dt][1] * linv);
            o.z = f2b(oacc[dt][2] * linv); o.w = f2b(oacc[dt][3] * linv);
            *(ushort4*)(op + dt * 16) = o;
        }
    }
}

// ---------------------------------------------------------------------------
// Workspace layout (62,988,288 B total):
//   xb/aout @ 0        (14,180,352)  [xb dead after gemm1; aout overlaps]
//   wqkvT  @ 14,180,352 ( 3,538,944)
//   wprojT @ 17,719,296 ( 1,179,648)
//   qkv    @ 18,898,944 (28,360,704)  [Q,K only; 1536-stride; RoPE applied]
//   VtG    @ 47,259,648 (15,728,640)  [written by gemm1 epilogue]
// ---------------------------------------------------------------------------
extern "C" void kernel_launch(void* const* d_in, const int* in_sizes, int n_in,
                              void* d_out, int out_size, void* d_ws, size_t ws_size,
                              hipStream_t stream) {
    const float* x      = (const float*)d_in[0];
    const float* cosp   = (const float*)d_in[1];
    const float* sinp   = (const float*)d_in[2];
    const float* w_qkv  = (const float*)d_in[3];
    const float* b_qkv  = (const float*)d_in[4];
    const float* w_proj = (const float*)d_in[5];
    const float* b_proj = (const float*)d_in[6];
    float* out = (float*)d_out;

    char* ws = (char*)d_ws;
    u16* xb     = (u16*)(ws);
    u16* aout   = (u16*)(ws);              // overlaps xb (dead after gemm1)
    u16* wqkvT  = (u16*)(ws + 14180352);
    u16* wprojT = (u16*)(ws + 17719296);
    u16* qkv    = (u16*)(ws + 18898944);
    u16* VtG    = (u16*)(ws + 47259648);

    f32_to_bf16<<<6924, 256, 0, stream>>>(x, xb, 7090176);
    transpose_w<<<dim3(96, 24), 256, 0, stream>>>(w_qkv, w_proj, wqkvT, wprojT);
    gemm_bt<2><<<dim3(73, 18), 512, 0, stream>>>(xb, wqkvT, b_qkv, qkv,
                                                 cosp, sinp, VtG, 9232, 2304, 768);
    attn2<<<dim3(1920), 256, 0, stream>>>(qkv, VtG, aout);
    gemm_bt<1><<<dim3(73, 6), 512, 0, stream>>>(aout, wprojT, b_proj, out,
                                                nullptr, nullptr, nullptr, 9232, 768, 768);
}

// Round 8
// 202.181 us; speedup vs baseline: 1.0934x; 1.0934x over previous
//
#include <hip/hip_runtime.h>
#include <stdint.h>

typedef unsigned short u16;
typedef __attribute__((ext_vector_type(8))) short bf16x8;
typedef __attribute__((ext_vector_type(4))) float f32x4;

#define MFMA16(a, b, c) __builtin_amdgcn_mfma_f32_16x16x32_bf16((a), (b), (c), 0, 0, 0)

__device__ __forceinline__ float b2f(u16 u) {
    union { unsigned int i; float f; } v; v.i = ((unsigned int)u) << 16; return v.f;
}
__device__ __forceinline__ u16 f2b(float f) {
    union { float f; unsigned int i; } v; v.f = f;
    unsigned int r = v.i + 0x7fffu + ((v.i >> 16) & 1u);
    return (u16)(r >> 16);
}
// native 2^x (v_exp_f32); schedulable asm, no memory clobber
__device__ __forceinline__ float exp2_fast(float x) {
    float r; __asm__("v_exp_f32 %0, %1" : "=v"(r) : "v"(x)); return r;
}

typedef __attribute__((address_space(1))) void gvoid;
typedef __attribute__((address_space(3))) void lvoid;
__device__ __forceinline__ void gld16(const void* g, void* l) {
    __builtin_amdgcn_global_load_lds((gvoid*)(void*)g, (lvoid*)l, 16, 0, 0);
}

// Panel-swizzled block mapping: 8-row-tile panels, col-major inside a panel.
// Keeps A's reuse window ~1.6 MB -> L2-resident (FETCH 139->52 MB, measured R5).
__device__ __forceinline__ void tile_from_bid(int bid, int nTM, int nTN,
                                              int& rt, int& ct) {
    const int PW = 8;
    const int full = nTM / PW;
    const int per = PW * nTN;
    int p = bid / per;
    int pw = PW;
    int rem = bid - p * per;
    if (p >= full) { p = full; rem = bid - full * per; pw = nTM - full * PW; }
    const int c = rem / pw;
    const int r = rem - c * pw;
    rt = p * PW + r;
    ct = c;
}

// ---------------------------------------------------------------------------
// fp32 -> bf16 elementwise convert (n multiple of 4)
// ---------------------------------------------------------------------------
__global__ __launch_bounds__(256) void f32_to_bf16(const float* __restrict__ in,
                                                   u16* __restrict__ out, int n) {
    const int i = (blockIdx.x * 256 + threadIdx.x) * 4;
    if (i + 3 < n) {
        const float4 v = *(const float4*)(in + i);
        ushort4 o;
        o.x = f2b(v.x); o.y = f2b(v.y); o.z = f2b(v.z); o.w = f2b(v.w);
        *(ushort4*)(out + i) = o;
    }
}

// ---------------------------------------------------------------------------
// merged transpose + fp32->bf16 for BOTH weights (one launch):
//   blockIdx.x <  72: w_qkv (768 x 2304) -> wqkvT (2304 x 768)
//   blockIdx.x >= 72: w_proj (768 x 768) -> wprojT (768 x 768)
// ---------------------------------------------------------------------------
__global__ __launch_bounds__(256) void transpose_w(const float* __restrict__ wqkv,
                                                   const float* __restrict__ wproj,
                                                   u16* __restrict__ outQ,
                                                   u16* __restrict__ outP) {
    __shared__ float tile[32][33];
    int bx = blockIdx.x;
    const float* in; u16* out; int C;
    if (bx < 72) { in = wqkv; out = outQ; C = 2304; }
    else         { bx -= 72; in = wproj; out = outP; C = 768; }
    const int R = 768;
    const int t = threadIdx.x;
    const int r = t >> 3, c4 = (t & 7) * 4;
    const int ir = blockIdx.y * 32 + r, ic = bx * 32 + c4;
    const float4 v = *(const float4*)(in + (size_t)ir * C + ic);
    tile[r][c4 + 0] = v.x; tile[r][c4 + 1] = v.y;
    tile[r][c4 + 2] = v.z; tile[r][c4 + 3] = v.w;
    __syncthreads();
    const int orow = bx * 32 + r, ocol = blockIdx.y * 32 + c4;
    ushort4 o;
    o.x = f2b(tile[c4 + 0][r]); o.y = f2b(tile[c4 + 1][r]);
    o.z = f2b(tile[c4 + 2][r]); o.w = f2b(tile[c4 + 3][r]);
    *(ushort4*)(out + (size_t)orow * R + ocol) = o;
}

// ---------------------------------------------------------------------------
// C = A(bf16)[M x K] * Bt(bf16)[N x K]^T + bias(f32)[N]
// R4-proven structure (58.9 us; R7 re-measure 63 us = same code, run noise):
// 128x128 tile, BK=64, 512 threads = 8 waves in 2x4 (wave 64x32, acc[4][2]),
// 2-buffer LDS (64 KB -> 2 blocks/CU), one __syncthreads per K-step.
// R6's 256x128 + 3-buffer counted-vmcnt at 1 block/CU REGRESSED (66 us):
// cross-block TLP > intra-block pipeline depth on this problem (R1, R6).
// Coalesced staging (8 rows x 128B full lines per wave-instr) + XOR
// involution on both sides; SQ_LDS_BANK_CONFLICT == 0 (measured R2/R4).
// MFMA operands swapped (D^T: l15 = row, quad*4+r = 4 cols).
// EPI: 1 = f32 store (stride N);
//      2 = fused qkv epilogue (block-uniform branch on col0):
//          Q/K tiles: bias + RoPE (intra-lane pairs) -> qkv (stride 1536);
//          V tiles: bias -> stores contiguous along l15 into VtG[bh][d][n].
// ---------------------------------------------------------------------------
template <int EPI>
__global__ __launch_bounds__(512) void gemm_bt(const u16* __restrict__ A,
                                               const u16* __restrict__ Bt,
                                               const float* __restrict__ bias,
                                               void* __restrict__ Cv,
                                               const float* __restrict__ cosp,
                                               const float* __restrict__ sinp,
                                               u16* __restrict__ VtG,
                                               int M, int N, int K) {
    __shared__ __align__(16) u16 As0[128 * 64];
    __shared__ __align__(16) u16 As1[128 * 64];
    __shared__ __align__(16) u16 Bs0[128 * 64];
    __shared__ __align__(16) u16 Bs1[128 * 64];

    const int t = threadIdx.x;
    const int lane = t & 63;
    const int wave = t >> 6;              // 0..7
    const int l15 = lane & 15, quad = lane >> 4;
    const int wm = wave >> 2;             // 0..1 (64 rows each)
    const int wn = wave & 3;              // 0..3 (32 cols each)

    int rt, ct;
    tile_from_bid(blockIdx.y * gridDim.x + blockIdx.x, gridDim.x, gridDim.y, rt, ct);
    const int row0 = rt * 128;
    const int col0 = ct * 128;

    const f32x4 fz = {0.f, 0.f, 0.f, 0.f};
    f32x4 acc[4][2];
#pragma unroll
    for (int i = 0; i < 4; ++i)
#pragma unroll
        for (int j = 0; j < 2; ++j) acc[i][j] = fz;

    // Coalesced staging map: chunk g -> row g>>3, LDS slot g&7,
    // global slot (g&7)^(row&7) (XOR source pre-swizzle; involution).
    const u16* Ap[2];
    const u16* Bp[2];
    int off[2];
#pragma unroll
    for (int n = 0; n < 2; ++n) {
        const int g = t + n * 512;
        const int row = g >> 3;
        const int slot = (g & 7) ^ (row & 7);
        int ar = row0 + row; if (ar > M - 1) ar = M - 1;   // clamp partial M tile
        Ap[n] = A + (size_t)ar * K + slot * 8;
        Bp[n] = Bt + (size_t)(col0 + row) * K + slot * 8;  // N % 128 == 0
        off[n] = g * 8;                                    // u16 units (linear LDS)
    }

#define STAGE(kt_, Ad, Bd) do {                                            \
        const int kb_ = (kt_) << 6;                                        \
        gld16(Ap[0] + kb_, (Ad) + off[0]);                                 \
        gld16(Ap[1] + kb_, (Ad) + off[1]);                                 \
        gld16(Bp[0] + kb_, (Bd) + off[0]);                                 \
        gld16(Bp[1] + kb_, (Bd) + off[1]);                                 \
    } while (0)

    // Row-major [row][64] LDS; k-granule XOR-swizzled by l15&7.
#define COMPUTE(Asb, Bsb) do {                                             \
        _Pragma("unroll")                                                  \
        for (int kk = 0; kk < 2; ++kk) {                                   \
            const int swk = ((kk * 4 + quad) ^ (l15 & 7)) * 8;             \
            bf16x8 af[4], bfr[2];                                          \
            _Pragma("unroll")                                              \
            for (int mi = 0; mi < 4; ++mi)                                 \
                af[mi] = *(const bf16x8*)((Asb) +                          \
                    ((wm * 4 + mi) * 16 + l15) * 64 + swk);                \
            _Pragma("unroll")                                              \
            for (int ni = 0; ni < 2; ++ni)                                 \
                bfr[ni] = *(const bf16x8*)((Bsb) +                         \
                    ((wn * 2 + ni) * 16 + l15) * 64 + swk);                \
            _Pragma("unroll")                                              \
            for (int mi = 0; mi < 4; ++mi)                                 \
                _Pragma("unroll")                                          \
                for (int ni = 0; ni < 2; ++ni)                             \
                    acc[mi][ni] = MFMA16(bfr[ni], af[mi], acc[mi][ni]);    \
        }                                                                  \
    } while (0)

    const int nKT = K >> 6;               // even (K % 128 == 0)
    STAGE(0, As0, Bs0);                   // prologue: tile 0 -> buf0
    __syncthreads();                      // (drains vmcnt0)

    for (int kt = 0; kt < nKT; kt += 2) {
        if (kt + 1 < nKT) STAGE(kt + 1, As1, Bs1);   // prefetch next -> buf1
        COMPUTE(As0, Bs0);                           // compute current (buf0)
        __syncthreads();                             // buf1 ready; buf0 released
        if (kt + 2 < nKT) STAGE(kt + 2, As0, Bs0);   // prefetch next -> buf0
        COMPUTE(As1, Bs1);                           // compute current (buf1)
        __syncthreads();                             // buf0 ready; buf1 released
    }
#undef STAGE
#undef COMPUTE

    // ---- epilogue (D^T layout: row = ...+l15, cols = colb..colb+3) ----
    if (EPI == 2) {
        if (col0 >= 1536) {
            // V tiles -> VtG[bh][d][n], stores contiguous along l15 (token n)
#pragma unroll
            for (int mi = 0; mi < 4; ++mi) {
                const int row = row0 + wm * 64 + mi * 16 + l15;
                if (row < M) {
                    const int bb = row / 577, n = row - bb * 577;
                    u16* vdst = VtG + (size_t)bb * 491520 + n;   // 12*64*640
#pragma unroll
                    for (int ni = 0; ni < 2; ++ni) {
                        const int colb = col0 + wn * 32 + ni * 16 + quad * 4;
                        const float4 bv = *(const float4*)(bias + colb);
#pragma unroll
                        for (int r = 0; r < 4; ++r) {
                            const int cv = colb + r - 1536;
                            vdst[(size_t)(cv >> 6) * 40960 + (cv & 63) * 640] =
                                f2b(acc[mi][ni][r] + ((const float*)&bv)[r]);
                        }
                    }
                }
            }
        } else {
            // Q/K tiles: bias + RoPE (intra-lane pairs) -> 1536-stride qkv
#pragma unroll
            for (int mi = 0; mi < 4; ++mi) {
                const int row = row0 + wm * 64 + mi * 16 + l15;
                if (row < M) {
                    const int bb = row / 577, n = row - bb * 577;
                    const bool hr = (n >= 1);
                    const float* cb = cosp + (size_t)(hr ? (n - 1) : 0) * 32;
                    const float* sb = sinp + (size_t)(hr ? (n - 1) : 0) * 32;
                    u16* outp = (u16*)Cv + (size_t)row * 1536;
#pragma unroll
                    for (int ni = 0; ni < 2; ++ni) {
                        const int colb = col0 + wn * 32 + ni * 16 + quad * 4;
                        const float4 bv = *(const float4*)(bias + colb);
                        const int pi = (colb & 63) >> 1;           // even
                        float2 c = *(const float2*)(cb + pi);
                        float2 s = *(const float2*)(sb + pi);
                        if (!hr) { c.x = 1.f; c.y = 1.f; s.x = 0.f; s.y = 0.f; }
                        const float v0 = acc[mi][ni][0] + bv.x;
                        const float v1 = acc[mi][ni][1] + bv.y;
                        const float v2 = acc[mi][ni][2] + bv.z;
                        const float v3 = acc[mi][ni][3] + bv.w;
                        ushort4 o;
                        o.x = f2b(v0 * c.x - v1 * s.x);
                        o.y = f2b(v0 * s.x + v1 * c.x);
                        o.z = f2b(v2 * c.y - v3 * s.y);
                        o.w = f2b(v2 * s.y + v3 * c.y);
                        *(ushort4*)(outp + colb) = o;
                    }
                }
            }
        }
    } else {
#pragma unroll
        for (int ni = 0; ni < 2; ++ni) {
            const int colb = col0 + wn * 32 + ni * 16 + quad * 4;
            const float4 bv = *(const float4*)(bias + colb);
#pragma unroll
            for (int mi = 0; mi < 4; ++mi) {
                const int row = row0 + wm * 64 + mi * 16 + l15;
                if (row < M) {
                    float4 o;
                    o.x = acc[mi][ni][0] + bv.x; o.y = acc[mi][ni][1] + bv.y;
                    o.z = acc[mi][ni][2] + bv.z; o.w = acc[mi][ni][3] + bv.w;
                    *(float4*)((float*)Cv + (size_t)row * N + colb) = o;
                }
            }
        }
    }
}

// ---------------------------------------------------------------------------
// Flash attention R15: 512 threads = 8 waves = 128 QUERIES per block
// (was 4 waves / 64 queries). Halves total K/V staging traffic+instructions
// (each thread stages 1 K-chunk + 1 V-chunk; each staged tile now serves
// 128 queries) and lightens per-thread address state (~13 VGPRs) so
// __launch_bounds__(512,8) caps VGPR at 64 -> 8 waves/SIMD. LDS = 8(K) +
// 8(V) + 18.4(P) = 34.8 KB -> 4 blocks/CU x 8 waves = 32 waves/CU (was 24).
// Grid 960 = 240 CUs x 4 blocks: fully resident in ONE shot (no tail).
// Swapped-operand softmax (lane owns one query), base-2 exp, packed P
// writes, XCD-chunk swizzle (960 = 8 x 120) -- all carried over.
// ---------------------------------------------------------------------------
#define PSTR 72
#define CEXP 0.18033688011112042f   /* 0.125 * log2(e) */

__global__ __launch_bounds__(512, 8) void attn2(const u16* __restrict__ qkv,
                                                const u16* __restrict__ VtG,
                                                u16* __restrict__ aout) {
    __shared__ __align__(16) u16 Ks[64 * 64];
    __shared__ __align__(16) u16 Vs[64 * 64];
    __shared__ __align__(16) u16 Pb[8 * 16 * PSTR];

    const int t = threadIdx.x;
    const int lane = t & 63, wave = t >> 6;          // wave 0..7
    const int l15 = lane & 15, quad = lane >> 4;

    // bijective XCD-chunk swizzle: 960 blocks = 8 XCDs x 120 contiguous
    const int bid = blockIdx.x;
    const int swz = (bid & 7) * 120 + (bid >> 3);
    const int bh = swz / 5, qt = swz - bh * 5;       // 5 q-tiles (128 q) per bh
    const int b = bh / 12, h = bh - b * 12;
    const u16* baseQ = qkv + (size_t)b * 577 * 1536 + h * 64;
    const u16* baseK = baseQ + 768;
    const u16* vbase = VtG + (size_t)bh * 64 * 640;

    const int mq = qt * 128 + wave * 16 + l15;       // this lane's query
    const int nq = mq < 577 ? mq : 576;
    bf16x8 aq[2];
    aq[0] = *(const bf16x8*)(baseQ + (size_t)nq * 1536 + quad * 8);
    aq[1] = *(const bf16x8*)(baseQ + (size_t)nq * 1536 + 32 + quad * 8);

    // staging map: chunk g = t (0..511) -> row g>>3, LDS slot g&7, global
    // slot (g&7)^(row&7). One wave-instr = 8 consecutive rows x 128B lines.
    const int r0 = t >> 3;
    const int s0 = (t & 7) ^ (r0 & 7);
    const int o0 = t * 8;                            // u16 units (16B chunks)
    const u16* Kp = baseK + (size_t)r0 * 1536 + s0 * 8;    // + kt*64*1536
    const u16* Vp = vbase + (size_t)r0 * 640 + s0 * 8;     // + kt*64

    // hoisted XOR'd k-granule offsets (row%8 == l15%8 on every read row)
    const int swk0 = (quad ^ (l15 & 7)) * 8;
    const int swk1 = ((4 + quad) ^ (l15 & 7)) * 8;

    u16* Pw = Pb + wave * 16 * PSTR;

    f32x4 oacc[4];
    const f32x4 fz = {0.f, 0.f, 0.f, 0.f};
#pragma unroll
    for (int i = 0; i < 4; ++i) oacc[i] = fz;
    float m1 = -1e30f;
    float l1 = 0.f;

#define ATT_TILE(kt_, MASKED) do {                                          \
        f32x4 sacc[4];                                                      \
        _Pragma("unroll")                                                   \
        for (int nt = 0; nt < 4; ++nt) {                                    \
            sacc[nt] = fz;                                                  \
            const bf16x8 bk0 = *(const bf16x8*)(Ks + (nt * 16 + l15) * 64 + swk0); \
            sacc[nt] = MFMA16(bk0, aq[0], sacc[nt]);                        \
            const bf16x8 bk1 = *(const bf16x8*)(Ks + (nt * 16 + l15) * 64 + swk1); \
            sacc[nt] = MFMA16(bk1, aq[1], sacc[nt]);                        \
        }                                                                   \
        if (MASKED) {                                                       \
            _Pragma("unroll")                                               \
            for (int nt = 0; nt < 4; ++nt)                                  \
                _Pragma("unroll")                                           \
                for (int r = 0; r < 4; ++r)                                 \
                    if (nt * 16 + quad * 4 + r > 0) sacc[nt][r] = -1e30f;   \
        }                                                                   \
        float mA = fmaxf(fmaxf(sacc[0][0], sacc[0][1]), fmaxf(sacc[0][2], sacc[0][3])); \
        float mB = fmaxf(fmaxf(sacc[1][0], sacc[1][1]), fmaxf(sacc[1][2], sacc[1][3])); \
        float mC = fmaxf(fmaxf(sacc[2][0], sacc[2][1]), fmaxf(sacc[2][2], sacc[2][3])); \
        float mD = fmaxf(fmaxf(sacc[3][0], sacc[3][1]), fmaxf(sacc[3][2], sacc[3][3])); \
        float mt = fmaxf(fmaxf(mA, mB), fmaxf(mC, mD));                     \
        mt = fmaxf(mt, __shfl_xor(mt, 16));                                 \
        mt = fmaxf(mt, __shfl_xor(mt, 32));                                 \
        const float mnew = fmaxf(m1, mt);                                   \
        const float alpha = exp2_fast((m1 - mnew) * CEXP);                  \
        m1 = mnew;                                                          \
        const float nmc = -mnew * CEXP;                                     \
        float lsum = 0.f;                                                   \
        _Pragma("unroll")                                                   \
        for (int nt = 0; nt < 4; ++nt) {                                    \
            const float p0 = exp2_fast(__builtin_fmaf(sacc[nt][0], CEXP, nmc)); \
            const float p1 = exp2_fast(__builtin_fmaf(sacc[nt][1], CEXP, nmc)); \
            const float p2 = exp2_fast(__builtin_fmaf(sacc[nt][2], CEXP, nmc)); \
            const float p3 = exp2_fast(__builtin_fmaf(sacc[nt][3], CEXP, nmc)); \
            lsum += (p0 + p1) + (p2 + p3);                                  \
            ushort4 pk;                                                     \
            pk.x = f2b(p0); pk.y = f2b(p1); pk.z = f2b(p2); pk.w = f2b(p3); \
            *(ushort4*)(Pw + l15 * PSTR + nt * 16 + quad * 4) = pk;         \
        }                                                                   \
        _Pragma("unroll")                                                   \
        for (int dt = 0; dt < 4; ++dt) {                                    \
            oacc[dt][0] *= alpha; oacc[dt][1] *= alpha;                     \
            oacc[dt][2] *= alpha; oacc[dt][3] *= alpha;                     \
        }                                                                   \
        __asm__ __volatile__("s_waitcnt lgkmcnt(0)" ::: "memory");          \
        _Pragma("unroll")                                                   \
        for (int kc = 0; kc < 2; ++kc) {                                    \
            const bf16x8 pf = *(const bf16x8*)(Pw + l15 * PSTR + kc * 32 + quad * 8); \
            const int swkv = kc ? swk1 : swk0;                              \
            _Pragma("unroll")                                               \
            for (int dt = 0; dt < 4; ++dt) {                                \
                const bf16x8 vf = *(const bf16x8*)(Vs + (dt * 16 + l15) * 64 + swkv); \
                oacc[dt] = MFMA16(vf, pf, oacc[dt]);                        \
            }                                                               \
        }                                                                   \
        lsum += __shfl_xor(lsum, 16);                                       \
        lsum += __shfl_xor(lsum, 32);                                       \
        l1 = l1 * alpha + lsum;                                             \
    } while (0)

    // single-buffer loop: stage -> publish -> compute; latency hidden by
    // 32 resident waves/CU (4 blocks x 8 waves).
    for (int kt = 0; kt < 9; ++kt) {
        gld16(Kp + (size_t)kt * 98304, Ks + o0);
        gld16(Vp + kt * 64, Vs + o0);
        __syncthreads();                  // vmcnt0 drain + publish
        ATT_TILE(kt, false);
        __syncthreads();                  // all reads done; buffer reusable
    }
    // kt=9 tail: all K rows clamp to key 576 (576 + row >= 576 for all rows)
    gld16(baseK + (size_t)576 * 1536 + s0 * 8, Ks + o0);
    gld16(Vp + 576, Vs + o0);
    __syncthreads();
    ATT_TILE(9, true);                    // only tile with invalid keys

#undef ATT_TILE

    // final: lane owns query l15; d = dt*16 + quad*4 + r (packed ushort4)
    const int n = qt * 128 + wave * 16 + l15;
    if (n < 577) {
        const float linv = 1.f / l1;
        u16* op = aout + ((size_t)b * 577 + n) * 768 + h * 64 + quad * 4;
#pragma unroll
        for (int dt = 0; dt < 4; ++dt) {
            ushort4 o;
            o.x = f2b(oacc[dt][0] * linv); o.y = f2b(oacc[dt][1] * linv);
            o.z = f2b(oacc[dt][2] * linv); o.w = f2b(oacc[dt][3] * linv);
            *(ushort4*)(op + dt * 16) = o;
        }
    }
}

// ---------------------------------------------------------------------------
// Workspace layout (62,988,288 B total):
//   xb/aout @ 0        (14,180,352)  [xb dead after gemm1; aout overlaps]
//   wqkvT  @ 14,180,352 ( 3,538,944)
//   wprojT @ 17,719,296 ( 1,179,648)
//   qkv    @ 18,898,944 (28,360,704)  [Q,K only; 1536-stride; RoPE applied]
//   VtG    @ 47,259,648 (15,728,640)  [written by gemm1 epilogue]
// ---------------------------------------------------------------------------
extern "C" void kernel_launch(void* const* d_in, const int* in_sizes, int n_in,
                              void* d_out, int out_size, void* d_ws, size_t ws_size,
                              hipStream_t stream) {
    const float* x      = (const float*)d_in[0];
    const float* cosp   = (const float*)d_in[1];
    const float* sinp   = (const float*)d_in[2];
    const float* w_qkv  = (const float*)d_in[3];
    const float* b_qkv  = (const float*)d_in[4];
    const float* w_proj = (const float*)d_in[5];
    const float* b_proj = (const float*)d_in[6];
    float* out = (float*)d_out;

    char* ws = (char*)d_ws;
    u16* xb     = (u16*)(ws);
    u16* aout   = (u16*)(ws);              // overlaps xb (dead after gemm1)
    u16* wqkvT  = (u16*)(ws + 14180352);
    u16* wprojT = (u16*)(ws + 17719296);
    u16* qkv    = (u16*)(ws + 18898944);
    u16* VtG    = (u16*)(ws + 47259648);

    f32_to_bf16<<<6924, 256, 0, stream>>>(x, xb, 7090176);
    transpose_w<<<dim3(96, 24), 256, 0, stream>>>(w_qkv, w_proj, wqkvT, wprojT);
    gemm_bt<2><<<dim3(73, 18), 512, 0, stream>>>(xb, wqkvT, b_qkv, qkv,
                                                 cosp, sinp, VtG, 9232, 2304, 768);
    attn2<<<dim3(960), 512, 0, stream>>>(qkv, VtG, aout);
    gemm_bt<1><<<dim3(73, 6), 512, 0, stream>>>(aout, wprojT, b_proj, out,
                                                nullptr, nullptr, nullptr, 9232, 768, 768);
}